// Round 1
// baseline (17493.694 us; speedup 1.0000x reference)
//
#include <hip/hip_runtime.h>
#include <math.h>

namespace {

constexpr int NB  = 256;    // batch
constexpr int NT  = 20;     // time steps
constexpr int NR  = 100;    // regions
constexpr int IND = 300;    // in_dim
constexpr int NH  = 1024;   // num_hid
constexpr int VD  = 2048;   // v_dim
constexpr int H4  = 4096;   // 4*num_hid
constexpr int VOC = 10000;  // vocab

__device__ __forceinline__ float sigm(float x) { return 1.f / (1.f + expf(-x)); }

// ---------------- generic fp32 GEMM: C = A@B (+bias) (+Cin) ----------------
// A [M,K] row-major lda; B [K,N] row-major ldb; C [M,N] ldc.
// bias (len N) optional; Cin optional with row stride ldcin (Cin==C allowed).
__global__ __launch_bounds__(256)
void gemm_f32(const float* __restrict__ Ap, int lda,
              const float* __restrict__ Bp, int ldb,
              float* __restrict__ Cp, int ldc,
              const float* __restrict__ bias,
              const float* __restrict__ Cin, int ldcin,
              int M, int N, int K)
{
  __shared__ float As[16][64];
  __shared__ float Bs[16][64];
  const int n0 = blockIdx.x * 64;
  const int m0 = blockIdx.y * 64;
  const int tid = threadIdx.x;
  const int tx = tid & 15, ty = tid >> 4;
  float acc[4][4] = {};

  for (int k0 = 0; k0 < K; k0 += 16) {
    // ---- load A tile 64(M) x 16(K): each thread 4 consecutive k ----
    {
      const int e = tid << 2;
      const int m = e >> 4;
      const int k = e & 15;
      const int gm = m0 + m, gk = k0 + k;
      float4 v = make_float4(0.f, 0.f, 0.f, 0.f);
      if (gm < M) {
        const float* src = Ap + (size_t)gm * lda + gk;
        if (gk + 3 < K) {
          v = *(const float4*)src;
        } else {
          if (gk     < K) v.x = src[0];
          if (gk + 1 < K) v.y = src[1];
          if (gk + 2 < K) v.z = src[2];
          if (gk + 3 < K) v.w = src[3];
        }
      }
      As[k    ][m] = v.x;
      As[k + 1][m] = v.y;
      As[k + 2][m] = v.z;
      As[k + 3][m] = v.w;
    }
    // ---- load B tile 16(K) x 64(N): each thread 4 consecutive n ----
    {
      const int e = tid << 2;
      const int k = e >> 6;
      const int n = e & 63;
      const int gk = k0 + k, gn = n0 + n;
      float4 v = make_float4(0.f, 0.f, 0.f, 0.f);
      if (gk < K) {
        const float* src = Bp + (size_t)gk * ldb + gn;
        if (gn + 3 < N) {
          v = *(const float4*)src;
        } else {
          if (gn     < N) v.x = src[0];
          if (gn + 1 < N) v.y = src[1];
          if (gn + 2 < N) v.z = src[2];
          if (gn + 3 < N) v.w = src[3];
        }
      }
      Bs[k][n    ] = v.x;
      Bs[k][n + 1] = v.y;
      Bs[k][n + 2] = v.z;
      Bs[k][n + 3] = v.w;
    }
    __syncthreads();
#pragma unroll
    for (int k = 0; k < 16; ++k) {
      const float a0 = As[k][ty * 4 + 0];
      const float a1 = As[k][ty * 4 + 1];
      const float a2 = As[k][ty * 4 + 2];
      const float a3 = As[k][ty * 4 + 3];
      const float b0 = Bs[k][tx * 4 + 0];
      const float b1 = Bs[k][tx * 4 + 1];
      const float b2 = Bs[k][tx * 4 + 2];
      const float b3 = Bs[k][tx * 4 + 3];
      acc[0][0] += a0 * b0; acc[0][1] += a0 * b1; acc[0][2] += a0 * b2; acc[0][3] += a0 * b3;
      acc[1][0] += a1 * b0; acc[1][1] += a1 * b1; acc[1][2] += a1 * b2; acc[1][3] += a1 * b3;
      acc[2][0] += a2 * b0; acc[2][1] += a2 * b1; acc[2][2] += a2 * b2; acc[2][3] += a2 * b3;
      acc[3][0] += a3 * b0; acc[3][1] += a3 * b1; acc[3][2] += a3 * b2; acc[3][3] += a3 * b3;
    }
    __syncthreads();
  }

#pragma unroll
  for (int i = 0; i < 4; ++i) {
    const int gm = m0 + ty * 4 + i;
    if (gm >= M) continue;
#pragma unroll
    for (int j = 0; j < 4; ++j) {
      const int gn = n0 + tx * 4 + j;
      if (gn >= N) continue;
      float v = acc[i][j];
      if (bias) v += bias[gn];
      if (Cin)  v += Cin[(size_t)gm * ldcin + gn];
      Cp[(size_t)gm * ldc + gn] = v;
    }
  }
}

// ---------------- feat_mean[b,d] = mean_r features[b,r,d] ----------------
__global__ void feat_mean_k(const float* __restrict__ feat, float* __restrict__ fm)
{
  const int idx = blockIdx.x * 256 + threadIdx.x;   // over NB*VD
  if (idx >= NB * VD) return;
  const int d = idx % VD;
  const int b = idx / VD;
  const float* base = feat + (size_t)b * NR * VD + d;
  float s = 0.f;
  for (int r = 0; r < NR; ++r) s += base[(size_t)r * VD];
  fm[idx] = s * (1.f / NR);
}

// ---------------- X[b,t,:]: t==0 -> v_rnn_inp[b], else emb[caption[b,t-1]] ----------------
__global__ void build_x_k(const int* __restrict__ cap, const float* __restrict__ emb,
                          const float* __restrict__ vinp, float* __restrict__ X)
{
  const int idx = blockIdx.x * 256 + threadIdx.x;   // over NB*NT*IND
  if (idx >= NB * NT * IND) return;
  const int d  = idx % IND;
  const int bt = idx / IND;
  const int t  = bt % NT;
  const int b  = bt / NT;
  float v;
  if (t == 0) v = vinp[b * IND + d];
  else        v = emb[(size_t)cap[b * (NT - 1) + (t - 1)] * IND + d];
  X[idx] = v;
}

// ---------------- pre[b,t,:] = FMG[b,:] (broadcast over t) ----------------
__global__ void bcast_pre_k(const float* __restrict__ fmg, float* __restrict__ pre)
{
  const int idx = blockIdx.x * 256 + threadIdx.x;   // over NB*NT*H4
  if (idx >= NB * NT * H4) return;
  const int n  = idx % H4;
  const int bt = idx / H4;
  const int b  = bt / NT;
  pre[idx] = fmg[(size_t)b * H4 + n];
}

// ---------------- LSTM pointwise ----------------
// gates [NB,H4] (i,f,g,o); h,c [NB,NH] updated in place.
// If outh != null, also write h into outh[b*NT*NH + n] (outh pre-offset by t*NH).
__global__ void lstm_pw_k(const float* __restrict__ gates, float* __restrict__ h,
                          float* __restrict__ c, float* __restrict__ outh)
{
  const int idx = blockIdx.x * 256 + threadIdx.x;   // over NB*NH
  if (idx >= NB * NH) return;
  const int n = idx & (NH - 1);
  const int b = idx >> 10;
  const float* g = gates + (size_t)b * H4;
  const float gi = g[n];
  const float gf = g[NH + n];
  const float gg = g[2 * NH + n];
  const float go = g[3 * NH + n];
  const float c2 = sigm(gf) * c[idx] + sigm(gi) * tanhf(gg);
  const float h2 = sigm(go) * tanhf(c2);
  c[idx] = c2;
  h[idx] = h2;
  if (outh) outh[(size_t)b * NT * NH + n] = h2;
}

// ---------------- attention logits: one wave per (b,r) ----------------
__global__ void att_logits_k(const float* __restrict__ va, const float* __restrict__ ha,
                             const float* __restrict__ Wa, const float* __restrict__ ba,
                             float* __restrict__ logits)
{
  const int wave = (blockIdx.x * 256 + threadIdx.x) >> 6;
  const int lane = threadIdx.x & 63;
  if (wave >= NB * NR) return;
  const int b = wave / NR;
  const float* vrow = va + (size_t)wave * NH;
  const float* hrow = ha + (size_t)b * NH;
  float s = 0.f;
  for (int j = lane; j < NH; j += 64)
    s += tanhf(vrow[j] + hrow[j]) * Wa[j];
  for (int o = 32; o; o >>= 1) s += __shfl_down(s, o);
  if (lane == 0) logits[wave] = s + ba[0];
}

// ---------------- softmax over regions, write att to output layout [b,t,r] ----------------
__global__ void att_softmax_k(const float* __restrict__ logits, float* __restrict__ att, int t)
{
  const int b  = blockIdx.x;
  const int tx = threadIdx.x;       // 128 threads
  const int lane = tx & 63, wid = tx >> 6;
  __shared__ float red[2];
  float v = (tx < NR) ? logits[b * NR + tx] : -3.4e38f;
  float m = v;
  for (int o = 32; o; o >>= 1) m = fmaxf(m, __shfl_xor(m, o));
  if (lane == 0) red[wid] = m;
  __syncthreads();
  m = fmaxf(red[0], red[1]);
  const float e = (tx < NR) ? expf(v - m) : 0.f;
  float s = e;
  for (int o = 32; o; o >>= 1) s += __shfl_xor(s, o);
  __syncthreads();
  if (lane == 0) red[wid] = s;
  __syncthreads();
  s = red[0] + red[1];
  if (tx < NR) att[(size_t)b * NT * NR + (size_t)t * NR + tx] = e / s;
}

// ---------------- feat_hat[b,d] = (1/R) * sum_r att[b,t,r]*features[b,r,d] ----------------
__global__ void feat_hat_k(const float* __restrict__ feat, const float* __restrict__ att,
                           float* __restrict__ fh, int t)
{
  const int idx = blockIdx.x * 256 + threadIdx.x;   // over NB*VD
  if (idx >= NB * VD) return;
  const int d = idx % VD;
  const int b = idx / VD;
  const float* arow = att + (size_t)b * NT * NR + (size_t)t * NR;
  const float* base = feat + (size_t)b * NR * VD + d;
  float s = 0.f;
  for (int r = 0; r < NR; ++r) s += arow[r] * base[(size_t)r * VD];
  fh[idx] = s * (1.f / NR);
}

inline void gemm(hipStream_t st, const float* A, int lda, const float* B, int ldb,
                 float* C, int ldc, const float* bias, const float* Cin, int ldcin,
                 int M, int N, int K)
{
  dim3 g((N + 63) / 64, (M + 63) / 64);
  gemm_f32<<<g, 256, 0, st>>>(A, lda, B, ldb, C, ldc, bias, Cin, ldcin, M, N, K);
}

} // namespace

extern "C" void kernel_launch(void* const* d_in, const int* in_sizes, int n_in,
                              void* d_out, int out_size, void* d_ws, size_t ws_size,
                              hipStream_t stream)
{
  // ---- inputs (setup_inputs order) ----
  const int*   caption = (const int*)  d_in[0];
  const float* feat    = (const float*)d_in[1];
  const float* emb     = (const float*)d_in[2];
  const float* W_vin   = (const float*)d_in[3];
  const float* b_vin   = (const float*)d_in[4];
  const float* W_ih_v  = (const float*)d_in[5];   // [3372, 4096]
  const float* W_hh_v  = (const float*)d_in[6];   // [1024, 4096]
  const float* b_v     = (const float*)d_in[7];
  const float* W_va    = (const float*)d_in[8];   // [2048, 1024]
  const float* b_va    = (const float*)d_in[9];
  const float* W_ha    = (const float*)d_in[10];  // [1024, 1024]
  const float* b_ha    = (const float*)d_in[11];
  const float* W_a     = (const float*)d_in[12];  // [1024, 1]
  const float* b_a     = (const float*)d_in[13];
  const float* W_ih_c  = (const float*)d_in[14];  // [3072, 4096]
  const float* W_hh_c  = (const float*)d_in[15];  // [1024, 4096]
  const float* b_c     = (const float*)d_in[16];
  const float* W_cls   = (const float*)d_in[17];  // [1024, 10000]
  const float* b_cls   = (const float*)d_in[18];

  float* out_repr = (float*)d_out;                         // [NB,NT,VOC]
  float* out_att  = out_repr + (size_t)NB * NT * VOC;      // [NB,NT,NR]

  // ---- workspace layout (floats) ----
  float* ws = (float*)d_ws;
  size_t off = 0;
  float* FM    = ws + off; off += (size_t)NB * VD;        // feat_mean
  float* VINP  = ws + off; off += (size_t)NB * IND;       // v_rnn_inp
  float* X     = ws + off; off += (size_t)NB * NT * IND;  // rnn inputs per step
  float* FMG   = ws + off; off += (size_t)NB * H4;        // feat_mean @ W_ih_v[0:2048] + b_v
  float* PRE   = ws + off; off += (size_t)NB * NT * H4;   // per-(b,t) precomputed gate part
  float* VA    = ws + off; off += (size_t)NB * NR * NH;   // region projection
  float* HV    = ws + off; off += (size_t)NB * NH;
  float* CV    = ws + off; off += (size_t)NB * NH;
  float* HC    = ws + off; off += (size_t)NB * NH;
  float* CC    = ws + off; off += (size_t)NB * NH;
  float* GATES = ws + off; off += (size_t)NB * H4;
  float* HA    = ws + off; off += (size_t)NB * NH;
  float* LOG   = ws + off; off += (size_t)NB * NR;
  float* FH    = ws + off; off += (size_t)NB * VD;
  float* OUTH  = ws + off; off += (size_t)NB * NT * NH;

  // zero-init recurrent state each call (harness does not re-poison between replays)
  hipMemsetAsync(HV, 0, (size_t)4 * NB * NH * sizeof(float), stream);

  // ---- setup phase ----
  feat_mean_k<<<(NB * VD + 255) / 256, 256, 0, stream>>>(feat, FM);

  // v_rnn_inp = feat_mean @ W_vin + b_vin            [256,300]
  gemm(stream, FM, VD, W_vin, IND, VINP, IND, b_vin, nullptr, 0, NB, IND, VD);

  build_x_k<<<(NB * NT * IND + 255) / 256, 256, 0, stream>>>(caption, emb, VINP, X);

  // FMG = feat_mean @ W_ih_v[0:2048,:] + b_v         [256,4096]
  gemm(stream, FM, VD, W_ih_v, H4, FMG, H4, b_v, nullptr, 0, NB, H4, VD);

  // PRE[b,t,:] = FMG[b,:] + X[b,t,:] @ W_ih_v[3072:3372,:]
  bcast_pre_k<<<(NB * NT * H4 + 255) / 256, 256, 0, stream>>>(FMG, PRE);
  gemm(stream, X, IND, W_ih_v + (size_t)3072 * H4, H4, PRE, H4,
       nullptr, PRE, H4, NB * NT, H4, IND);

  // VA = features @ W_va + b_va                      [25600,1024]
  gemm(stream, feat, VD, W_va, NH, VA, NH, b_va, nullptr, 0, NB * NR, NH, VD);

  // ---- sequential decode ----
  for (int t = 0; t < NT; ++t) {
    // gates_v = PRE[:,t,:] + h_c @ W_ih_v[2048:3072,:] + h_v @ W_hh_v
    gemm(stream, HC, NH, W_ih_v + (size_t)2048 * H4, H4, GATES, H4,
         nullptr, PRE + (size_t)t * H4, NT * H4, NB, H4, NH);
    gemm(stream, HV, NH, W_hh_v, H4, GATES, H4, nullptr, GATES, H4, NB, H4, NH);
    lstm_pw_k<<<(NB * NH + 255) / 256, 256, 0, stream>>>(GATES, HV, CV, nullptr);

    // ha = h_v @ W_ha + b_ha
    gemm(stream, HV, NH, W_ha, NH, HA, NH, b_ha, nullptr, 0, NB, NH, NH);

    // attention
    att_logits_k<<<(NB * NR * 64 + 255) / 256, 256, 0, stream>>>(VA, HA, W_a, b_a, LOG);
    att_softmax_k<<<NB, 128, 0, stream>>>(LOG, out_att, t);
    feat_hat_k<<<(NB * VD + 255) / 256, 256, 0, stream>>>(feat, out_att, FH, t);

    // gates_c = feat_hat @ W_ih_c[0:2048,:] + h_v @ W_ih_c[2048:3072,:] + h_c @ W_hh_c + b_c
    gemm(stream, FH, VD, W_ih_c, H4, GATES, H4, b_c, nullptr, 0, NB, H4, VD);
    gemm(stream, HV, NH, W_ih_c + (size_t)2048 * H4, H4, GATES, H4,
         nullptr, GATES, H4, NB, H4, NH);
    gemm(stream, HC, NH, W_hh_c, H4, GATES, H4, nullptr, GATES, H4, NB, H4, NH);
    lstm_pw_k<<<(NB * NH + 255) / 256, 256, 0, stream>>>(GATES, HC, CC, OUTH + (size_t)t * NH);
  }

  // ---- classifier: repr = OUTH @ W_cls + b_cls     [5120,10000]
  gemm(stream, OUTH, NH, W_cls, VOC, out_repr, VOC, b_cls, nullptr, 0, NB * NT, VOC, NH);
}